// Round 14
// baseline (97.406 us; speedup 1.0000x reference)
//
#include <hip/hip_runtime.h>

// CTC batch cost (keras ctc_batch_cost semantics), blank = C-1.
// SINGLE wave64 per batch element (256 blocks x 64 threads).
// Lane L owns states 4L..4L+3; lane 63 also owns state 256.
// f64 probability-domain DP (no transcendentals in the loop), exact
// power-of-2 rescale every CK=12 steps via DPP exponent-max reduce.
// The SAME wave issues global_load_lds chunks (25 VMEM/chunk) into a
// 4-slot f32 LDS ring and gates consumption with counted s_waitcnt
// vmcnt(25) -- no producer wave, no s_barriers, no cross-wave skew
// (r13's ~48cy/step barrier tax). ISSUE(i+2) sits at the END of each
// iteration so even a compiler-inserted conservative vmcnt(0) before
// the chunk's ds_reads only waits on loads issued a full iteration ago.
// In-flight data lives in LDS: rounds 7-10 proved asm register buffers
// corrupt execution beyond ~48 in flight.

constexpr int   Tn    = 1024;
constexpr int   Cc    = 128;
constexpr int   Ln    = 128;
constexpr float EPSf  = 1e-7f;
constexpr int   CK    = 12;    // rows per chunk == rescale period
constexpr int   NSLOT = 4;     // LDS ring slots

__device__ __forceinline__ int dpp_max_i32(int m) {
    int o;
    o = __builtin_amdgcn_update_dpp(0, m, 0x111, 0xf, 0xf, false); m = o > m ? o : m; // row_shr:1
    o = __builtin_amdgcn_update_dpp(0, m, 0x112, 0xf, 0xf, false); m = o > m ? o : m; // row_shr:2
    o = __builtin_amdgcn_update_dpp(0, m, 0x114, 0xf, 0xf, false); m = o > m ? o : m; // row_shr:4
    o = __builtin_amdgcn_update_dpp(0, m, 0x118, 0xf, 0xf, false); m = o > m ? o : m; // row_shr:8
    o = __builtin_amdgcn_update_dpp(0, m, 0x142, 0xf, 0xf, false); m = o > m ? o : m; // row_bcast:15
    o = __builtin_amdgcn_update_dpp(0, m, 0x143, 0xf, 0xf, false); m = o > m ? o : m; // row_bcast:31
    return m;   // lane 63 holds the wave max
}

// lane L gets lane L-1's value; lane 0 gets exact +0.0 (bound_ctrl=1).
__device__ __forceinline__ double dpp_shr1_f64(double x) {
    const int lo = __double2loint(x), hi = __double2hiint(x);
    const int slo = __builtin_amdgcn_update_dpp(0, lo, 0x138, 0xf, 0xf, true); // wave_shr:1
    const int shi = __builtin_amdgcn_update_dpp(0, hi, 0x138, 0xf, 0xf, true);
    return __hiloint2double(shi, slo);
}

__global__ __launch_bounds__(64, 1)
void ctc_fwd_kernel(const int*   __restrict__ y_true,
                    const float* __restrict__ y_pred,
                    const int*   __restrict__ in_len,
                    const int*   __restrict__ lab_len,
                    float*       __restrict__ out)
{
    const int L  = threadIdx.x;          // 0..63
    const int b  = blockIdx.x;
    const int il = in_len[b];
    const int ll = lab_len[b];
    const int blank = Cc - 1;

    const int* yb   = y_true + (size_t)b * Ln;
    const int  lab1 = yb[2 * L];                       // label for state 4L+1
    const int  lab2 = yb[2 * L + 1];                   // label for state 4L+3
    const int  labp = (L > 0) ? yb[2 * L - 1] : -1;

    const double skm1 = ((L > 0) && (lab1 != blank) && (lab1 != labp)) ? 1.0 : 0.0;
    const double skm3 = ((lab2 != blank) && (lab2 != lab1)) ? 1.0 : 0.0;

    const float* base = y_pred + (size_t)b * Tn * Cc;
    const int steps = (il > 0) ? (il - 1) : 0;         // updates run t = 1 .. il-1
    const int nfull = steps / CK;
    const int nch   = (steps + CK - 1) / CK;

    __shared__ float  f32L1[NSLOT][CK][64];
    __shared__ float  f32L2[NSLOT][CK][64];
    __shared__ float  f32BK[NSLOT][CK];
    __shared__ double sA[258];

#define WAIT_VM(n) do {                                                 \
    __builtin_amdgcn_sched_barrier(0);                                  \
    asm volatile("s_waitcnt vmcnt(" #n ")");                            \
    __builtin_amdgcn_sched_barrier(0);                                  \
} while (0)

    // 25 VMEM per chunk: 1 blank (lanes 0..11 cover the 12 rows), 12+12 label rows.
#define ISSUE_CHUNK(k) do {                                             \
    const int slot_ = (k) & (NSLOT - 1);                                \
    {                                                                   \
        int tb_ = 1 + (k) * CK + L; if (tb_ > steps) tb_ = steps; if (tb_ < 0) tb_ = 0; \
        const float* g_ = base + (size_t)tb_ * Cc + blank;              \
        if (L < CK)                                                     \
            __builtin_amdgcn_global_load_lds(                           \
                (const __attribute__((address_space(1))) void*)g_,      \
                (__attribute__((address_space(3))) void*)&f32BK[slot_][0], 4, 0, 0); \
    }                                                                   \
    _Pragma("unroll")                                                   \
    for (int r_ = 0; r_ < CK; ++r_) {                                   \
        int t_ = 1 + (k) * CK + r_; if (t_ > steps) t_ = steps; if (t_ < 0) t_ = 0; \
        const float* row_ = base + (size_t)t_ * Cc;                     \
        __builtin_amdgcn_global_load_lds(                               \
            (const __attribute__((address_space(1))) void*)(row_ + lab1), \
            (__attribute__((address_space(3))) void*)&f32L1[slot_][r_][0], 4, 0, 0); \
        __builtin_amdgcn_global_load_lds(                               \
            (const __attribute__((address_space(1))) void*)(row_ + lab2), \
            (__attribute__((address_space(3))) void*)&f32L2[slot_][r_][0], 4, 0, 0); \
    }                                                                   \
} while (0)

#define DPSTEP(qb_, q1_, q2_) do {                                      \
    const double pa3_ = dpp_shr1_f64(a3v);                              \
    const double n0_ = (a0 + pa3_) * (qb_);                             \
    const double n1_ = fma(skm1, pa3_, a0 + a1v) * (q1_);               \
    const double n2_ = (a2v + a1v) * (qb_);                             \
    const double n3_ = fma(skm3, a1v, a3v + a2v) * (q2_);               \
    const double n4_ = (a4v + a3v) * (qb_);                             \
    a0 = n0_; a1v = n1_; a2v = n2_; a3v = n3_; a4v = n4_;               \
} while (0)

#define RESCALE() do {                                                  \
    double m_ = fmax(fmax(a0, a1v), fmax(a2v, a3v)); m_ = fmax(m_, a4v);\
    int be_ = (__double2hiint(m_) >> 20) & 0x7ff;                       \
    be_ = dpp_max_i32(be_);                                             \
    const int emax_ = __builtin_amdgcn_readlane(be_, 63);               \
    const double sc_ = __hiloint2double((2046 - emax_) << 20, 0);       \
    a0 *= sc_; a1v *= sc_; a2v *= sc_; a3v *= sc_; a4v *= sc_;          \
    shift += emax_ - 1023;                                              \
} while (0)

    // ---- t = 0 init (prob domain, f64) ----
    double a0 = 0.0, a1v = 0.0, a2v = 0.0, a3v = 0.0, a4v = 0.0;
    if (L == 0) {
        a0  = (double)(base[blank] + EPSf);
        a1v = (ll > 0) ? (double)(base[lab1] + EPSf) : 0.0;
    }
    int shift = 0;

    // Prologue: chunks 0 and 1 in flight (50 outstanding <= 63).
    ISSUE_CHUNK(0);
    ISSUE_CHUNK(1);

    for (int i = 0; i < nch; ++i) {
        // Gate: chunk i landed (in-order vmcnt). Steady state: free.
        if (i + 1 < nch) WAIT_VM(25); else WAIT_VM(0);

        const int slot = i & (NSLOT - 1);

        // Batch-read + convert the whole chunk into registers (static idx).
        double qb[CK], q1[CK], q2[CK];
#pragma unroll
        for (int r = 0; r < CK; ++r) {
            qb[r] = (double)(f32BK[slot][r]    + EPSf);
            q1[r] = (double)(f32L1[slot][r][L] + EPSf);
            q2[r] = (double)(f32L2[slot][r][L] + EPSf);
        }

        if (i < nfull) {
#pragma unroll
            for (int r = 0; r < CK; ++r)
                DPSTEP(qb[r], q1[r], q2[r]);
        } else {
#pragma unroll
            for (int r = 0; r < CK; ++r) {
                if (1 + i * CK + r <= steps)
                    DPSTEP(qb[r], q1[r], q2[r]);
            }
        }

        // Issue chunk i+2 LATE: by the time iteration i+1 reads its chunk,
        // these loads are ~a full iteration old (covers even a forced drain).
        if (i + 2 < nch) ISSUE_CHUNK(i + 2);   // back to <= 50 outstanding

        RESCALE();                   // every 12 steps (exact pow-2)
    }

    // ---- readout (single wave; DS ops in-order within the wave) ----
    sA[4 * L + 0] = a0;
    sA[4 * L + 1] = a1v;
    sA[4 * L + 2] = a2v;
    sA[4 * L + 3] = a3v;
    if (L == 63) sA[256] = a4v;

    if (L == 0) {
        const int end = 2 * ll;
        const double ae = sA[end];
        int pi = end - 1; if (pi < 0) pi = 0;
        double ap = sA[pi];
        if (ll <= 0) ap = 0.0;
        const double s  = ae + ap;
        const double lg = log2(s) + (double)shift;
        out[b] = (float)(-0.6931471805599453 * lg);
    }

#undef WAIT_VM
#undef ISSUE_CHUNK
#undef DPSTEP
#undef RESCALE
}

extern "C" void kernel_launch(void* const* d_in, const int* in_sizes, int n_in,
                              void* d_out, int out_size, void* d_ws, size_t ws_size,
                              hipStream_t stream) {
    const int*   y_true  = (const int*)  d_in[0];
    const float* y_pred  = (const float*)d_in[1];
    const int*   in_len  = (const int*)  d_in[2];
    const int*   lab_len = (const int*)  d_in[3];
    float*       out     = (float*)      d_out;

    ctc_fwd_kernel<<<dim3(256), dim3(64), 0, stream>>>(y_true, y_pred, in_len, lab_len, out);
}

// Round 15
// 58.494 us; speedup vs baseline: 1.6652x; 1.6652x over previous
//
#include <hip/hip_runtime.h>

// CTC batch cost (keras ctc_batch_cost semantics), blank = C-1.
// 256 blocks x 128 threads: wave 0 = DP consumer, wave 1 = producer.
// Lane L owns states 4L..4L+3; lane 63 also owns state 256.
// f64 probability-domain DP (no transcendentals in the loop), exact
// power-of-2 rescale every CK=15 steps via DPP exponent-max reduce.
// Producer: 31 global_load_lds per chunk into a 4-slot f32 LDS ring,
// depth-2 (62 outstanding <= 63), counted s_waitcnt vmcnt(31).
// Consumer: batch-reads chunk i into registers, THEN barriers, THEN runs
// the DP -- the producer's gate-wait+barrier overlap the consumer's DP
// phase instead of serializing after it (r13 lost ~40cy/step there).
// r14's single-wave gating REVERTED: compiler inserts vmcnt(0) drains
// between same-wave LDS-DMA and ds_read (58->97us regression).
// All staging lives in LDS: asm register buffers corrupt execution
// beyond ~48 in flight (rounds 7-10).

constexpr int   Tn    = 1024;
constexpr int   Cc    = 128;
constexpr int   Ln    = 128;
constexpr float EPSf  = 1e-7f;
constexpr int   CK    = 15;    // rows per chunk == rescale period
constexpr int   NSLOT = 4;     // LDS ring slots

__device__ __forceinline__ int dpp_max_i32(int m) {
    int o;
    o = __builtin_amdgcn_update_dpp(0, m, 0x111, 0xf, 0xf, false); m = o > m ? o : m; // row_shr:1
    o = __builtin_amdgcn_update_dpp(0, m, 0x112, 0xf, 0xf, false); m = o > m ? o : m; // row_shr:2
    o = __builtin_amdgcn_update_dpp(0, m, 0x114, 0xf, 0xf, false); m = o > m ? o : m; // row_shr:4
    o = __builtin_amdgcn_update_dpp(0, m, 0x118, 0xf, 0xf, false); m = o > m ? o : m; // row_shr:8
    o = __builtin_amdgcn_update_dpp(0, m, 0x142, 0xf, 0xf, false); m = o > m ? o : m; // row_bcast:15
    o = __builtin_amdgcn_update_dpp(0, m, 0x143, 0xf, 0xf, false); m = o > m ? o : m; // row_bcast:31
    return m;   // lane 63 holds the wave max
}

// lane L gets lane L-1's value; lane 0 gets exact +0.0 (bound_ctrl=1).
__device__ __forceinline__ double dpp_shr1_f64(double x) {
    const int lo = __double2loint(x), hi = __double2hiint(x);
    const int slo = __builtin_amdgcn_update_dpp(0, lo, 0x138, 0xf, 0xf, true); // wave_shr:1
    const int shi = __builtin_amdgcn_update_dpp(0, hi, 0x138, 0xf, 0xf, true);
    return __hiloint2double(shi, slo);
}

__global__ __launch_bounds__(128, 1)
void ctc_fwd_kernel(const int*   __restrict__ y_true,
                    const float* __restrict__ y_pred,
                    const int*   __restrict__ in_len,
                    const int*   __restrict__ lab_len,
                    float*       __restrict__ out)
{
    const int tid = threadIdx.x;
    const int L   = tid & 63;            // lane within wave
    const int b   = blockIdx.x;
    const int il  = in_len[b];
    const int ll  = lab_len[b];
    const int blank = Cc - 1;

    const int* yb   = y_true + (size_t)b * Ln;
    const int  lab1 = yb[2 * L];                       // label for state 4L+1
    const int  lab2 = yb[2 * L + 1];                   // label for state 4L+3

    const float* base = y_pred + (size_t)b * Tn * Cc;
    const int steps = (il > 0) ? (il - 1) : 0;         // updates run t = 1 .. il-1
    const int nfull = steps / CK;
    const int nch   = (steps + CK - 1) / CK;

    __shared__ float  f32L1[NSLOT][CK][64];
    __shared__ float  f32L2[NSLOT][CK][64];
    __shared__ float  f32BK[NSLOT][CK];
    __shared__ double sA[258];

#define BARRIER() do {                                                  \
    __builtin_amdgcn_sched_barrier(0);                                  \
    asm volatile("" ::: "memory");                                      \
    __builtin_amdgcn_s_barrier();                                       \
    asm volatile("" ::: "memory");                                      \
    __builtin_amdgcn_sched_barrier(0);                                  \
} while (0)

#define WAIT_VM(n) do {                                                 \
    __builtin_amdgcn_sched_barrier(0);                                  \
    asm volatile("s_waitcnt vmcnt(" #n ")");                            \
    __builtin_amdgcn_sched_barrier(0);                                  \
} while (0)

    if (tid >= 64) {
        // ---------------- producer wave ----------------
        // 31 VMEM per chunk: 1 blank (lanes 0..14 cover rows), 15+15 label rows.
#define ISSUE_CHUNK(k) do {                                             \
    const int slot_ = (k) & (NSLOT - 1);                                \
    {                                                                   \
        int tb_ = 1 + (k) * CK + L; if (tb_ > steps) tb_ = steps; if (tb_ < 0) tb_ = 0; \
        const float* g_ = base + (size_t)tb_ * Cc + blank;              \
        if (L < CK)                                                     \
            __builtin_amdgcn_global_load_lds(                           \
                (const __attribute__((address_space(1))) void*)g_,      \
                (__attribute__((address_space(3))) void*)&f32BK[slot_][0], 4, 0, 0); \
    }                                                                   \
    _Pragma("unroll")                                                   \
    for (int r_ = 0; r_ < CK; ++r_) {                                   \
        int t_ = 1 + (k) * CK + r_; if (t_ > steps) t_ = steps; if (t_ < 0) t_ = 0; \
        const float* row_ = base + (size_t)t_ * Cc;                     \
        __builtin_amdgcn_global_load_lds(                               \
            (const __attribute__((address_space(1))) void*)(row_ + lab1), \
            (__attribute__((address_space(3))) void*)&f32L1[slot_][r_][0], 4, 0, 0); \
        __builtin_amdgcn_global_load_lds(                               \
            (const __attribute__((address_space(1))) void*)(row_ + lab2), \
            (__attribute__((address_space(3))) void*)&f32L2[slot_][r_][0], 4, 0, 0); \
    }                                                                   \
} while (0)

        ISSUE_CHUNK(0);
        ISSUE_CHUNK(1);              // 62 outstanding
        WAIT_VM(31);                 // chunk 0 landed
        BARRIER();                   // prologue rendezvous
        for (int i = 0; i < nch; ++i) {
            if (i + 2 < nch) {
                ISSUE_CHUNK(i + 2);  // <= 62 outstanding
                WAIT_VM(31);         // chunk i+1 landed (in-order)
            } else {
                WAIT_VM(0);          // tail: drain everything
            }
            BARRIER();
        }
        return;
#undef ISSUE_CHUNK
    }

    // ---------------- consumer wave (DP) ----------------
    const int  labp = (L > 0) ? yb[2 * L - 1] : -1;
    const double skm1 = ((L > 0) && (lab1 != blank) && (lab1 != labp)) ? 1.0 : 0.0;
    const double skm3 = ((lab2 != blank) && (lab2 != lab1)) ? 1.0 : 0.0;

    double a0 = 0.0, a1v = 0.0, a2v = 0.0, a3v = 0.0, a4v = 0.0;
    if (L == 0) {
        a0  = (double)(base[blank] + EPSf);
        a1v = (ll > 0) ? (double)(base[lab1] + EPSf) : 0.0;
    }
    int shift = 0;

#define DPSTEP(qb_, q1_, q2_) do {                                      \
    const double pa3_ = dpp_shr1_f64(a3v);                              \
    const double n0_ = (a0 + pa3_) * (qb_);                             \
    const double n1_ = fma(skm1, pa3_, a0 + a1v) * (q1_);               \
    const double n2_ = (a2v + a1v) * (qb_);                             \
    const double n3_ = fma(skm3, a1v, a3v + a2v) * (q2_);               \
    const double n4_ = (a4v + a3v) * (qb_);                             \
    a0 = n0_; a1v = n1_; a2v = n2_; a3v = n3_; a4v = n4_;               \
} while (0)

#define RESCALE() do {                                                  \
    double m_ = fmax(fmax(a0, a1v), fmax(a2v, a3v)); m_ = fmax(m_, a4v);\
    int be_ = (__double2hiint(m_) >> 20) & 0x7ff;                       \
    be_ = dpp_max_i32(be_);                                             \
    const int emax_ = __builtin_amdgcn_readlane(be_, 63);               \
    const double sc_ = __hiloint2double((2046 - emax_) << 20, 0);       \
    a0 *= sc_; a1v *= sc_; a2v *= sc_; a3v *= sc_; a4v *= sc_;          \
    shift += emax_ - 1023;                                              \
} while (0)

    BARRIER();                       // prologue: chunk 0 ready

    for (int i = 0; i < nch; ++i) {
        const int slot = i & (NSLOT - 1);

        // Batch-read + convert chunk i into registers (static idx) BEFORE
        // the barrier: the producer's wait+barrier then overlap our DP.
        double qb[CK], q1[CK], q2[CK];
#pragma unroll
        for (int r = 0; r < CK; ++r) {
            qb[r] = (double)(f32BK[slot][r]    + EPSf);
            q1[r] = (double)(f32L1[slot][r][L] + EPSf);
            q2[r] = (double)(f32L2[slot][r][L] + EPSf);
        }

        BARRIER();                   // chunk i+1 ready; slot rotation safe

        if (i < nfull) {
#pragma unroll
            for (int r = 0; r < CK; ++r)
                DPSTEP(qb[r], q1[r], q2[r]);
        } else {
#pragma unroll
            for (int r = 0; r < CK; ++r) {
                if (1 + i * CK + r <= steps)
                    DPSTEP(qb[r], q1[r], q2[r]);
            }
        }
        RESCALE();                   // every 15 steps (exact pow-2)
    }

    // ---- readout (single wave; DS ops in-order within the wave) ----
    sA[4 * L + 0] = a0;
    sA[4 * L + 1] = a1v;
    sA[4 * L + 2] = a2v;
    sA[4 * L + 3] = a3v;
    if (L == 63) sA[256] = a4v;

    if (L == 0) {
        const int end = 2 * ll;
        const double ae = sA[end];
        int pi = end - 1; if (pi < 0) pi = 0;
        double ap = sA[pi];
        if (ll <= 0) ap = 0.0;
        const double s  = ae + ap;
        const double lg = log2(s) + (double)shift;
        out[b] = (float)(-0.6931471805599453 * lg);
    }

#undef BARRIER
#undef WAIT_VM
#undef DPSTEP
#undef RESCALE
}

extern "C" void kernel_launch(void* const* d_in, const int* in_sizes, int n_in,
                              void* d_out, int out_size, void* d_ws, size_t ws_size,
                              hipStream_t stream) {
    const int*   y_true  = (const int*)  d_in[0];
    const float* y_pred  = (const float*)d_in[1];
    const int*   in_len  = (const int*)  d_in[2];
    const int*   lab_len = (const int*)  d_in[3];
    float*       out     = (float*)      d_out;

    ctc_fwd_kernel<<<dim3(256), dim3(128), 0, stream>>>(y_true, y_pred, in_len, lab_len, out);
}